// Round 20
// baseline (1109.337 us; speedup 1.0000x reference)
//
#include <hip/hip_runtime.h>
#include <math.h>

#define T_TOK 4096
#define DM 1024
#define HID 4096
#define NEXP 8
#define MAXT 23   // max total 256-row tiles: 4096/256 + 7

typedef unsigned short u16;
typedef __attribute__((ext_vector_type(8))) short short8;
typedef __attribute__((ext_vector_type(4))) float f32x4;

__device__ __forceinline__ u16 f2bf(float f){
  unsigned u = __float_as_uint(f);
  u += 0x7FFF + ((u >> 16) & 1);
  return (u16)(u >> 16);
}

// ---- workspace layout (byte offsets) ----
#define GATE_OFF   0u          // float[4096]
#define CNT_OFF    16384u      // int[8]
#define LIST_OFF   16512u      // int[8][4096]
#define PROBS_OFF  147584u     // float[4096][8]
#define XB_OFF     278656u     // bf16[4096][1024]
#define H_OFF      8667264u    // bf16[4096][4096]
#define PART_OFF   42221696u   // float[4][4096][1024] = 64MB

__device__ __forceinline__ void glds16(const void* g, void* l){
  __builtin_amdgcn_global_load_lds((const __attribute__((address_space(1))) void*)g,
                                   (__attribute__((address_space(3))) void*)l, 16, 0, 0);
}

__global__ void zero_cnt_kernel(int* cnt){
  if (threadIdx.x < NEXP) cnt[threadIdx.x] = 0;
}

// one wave per token: gating + routing + x->bf16 conversion
__global__ __launch_bounds__(256) void gate_kernel(
    const float* __restrict__ x, const float* __restrict__ gw,
    float* __restrict__ gateo, int* __restrict__ cnt, int* __restrict__ list,
    float* __restrict__ probs, u16* __restrict__ xb)
{
  int tid = threadIdx.x;
  int lane = tid & 63;
  int w = tid >> 6;
  int t = blockIdx.x * 4 + w;

  const float4* x4 = (const float4*)(x + (size_t)t * DM);
  const float4* g4 = (const float4*)gw;

  float acc[8] = {0,0,0,0,0,0,0,0};
  #pragma unroll
  for (int i = 0; i < 4; i++){
    int p = i * 64 + lane;
    float4 xv = x4[p];
    ushort4 pk;
    pk.x = f2bf(xv.x); pk.y = f2bf(xv.y); pk.z = f2bf(xv.z); pk.w = f2bf(xv.w);
    *(ushort4*)&xb[(size_t)t * DM + (size_t)p * 4] = pk;
    #pragma unroll
    for (int e = 0; e < NEXP; e++){
      float4 gv = g4[e * 256 + p];
      acc[e] += xv.x * gv.x + xv.y * gv.y + xv.z * gv.z + xv.w * gv.w;
    }
  }
  #pragma unroll
  for (int e = 0; e < NEXP; e++){
    #pragma unroll
    for (int off = 32; off; off >>= 1)
      acc[e] += __shfl_xor(acc[e], off);
  }
  if (lane == 0){
    float mx = acc[0];
    #pragma unroll
    for (int e = 1; e < NEXP; e++) mx = fmaxf(mx, acc[e]);
    float p[8]; float s = 0.f;
    #pragma unroll
    for (int e = 0; e < NEXP; e++){ p[e] = expf(acc[e] - mx); s += p[e]; }
    float inv = 1.f / s;
    int be = 0; float bp = p[0];
    #pragma unroll
    for (int e = 1; e < NEXP; e++){ if (p[e] > bp){ bp = p[e]; be = e; } }
    #pragma unroll
    for (int e = 0; e < NEXP; e++) probs[(size_t)t * 8 + e] = p[e] * inv;
    gateo[t] = bp * inv;
    int pos = atomicAdd(&cnt[be], 1);
    list[be * T_TOK + pos] = t;
  }
}

// deterministic aux-loss reduction, one block
__global__ __launch_bounds__(256) void aux_kernel(
    const float* __restrict__ probs, const int* __restrict__ cnt,
    float* __restrict__ aux_out)
{
  __shared__ float sm[256 * 8];
  int tid = threadIdx.x;
  float s[8] = {0,0,0,0,0,0,0,0};
  for (int i = 0; i < 16; i++){
    int t = i * 256 + tid;
    #pragma unroll
    for (int e = 0; e < 8; e++) s[e] += probs[(size_t)t * 8 + e];
  }
  #pragma unroll
  for (int e = 0; e < 8; e++) sm[tid * 8 + e] = s[e];
  __syncthreads();
  for (int st = 128; st; st >>= 1){
    if (tid < st){
      #pragma unroll
      for (int e = 0; e < 8; e++) sm[tid * 8 + e] += sm[(tid + st) * 8 + e];
    }
    __syncthreads();
  }
  if (tid == 0){
    float a = 0.f;
    #pragma unroll
    for (int e = 0; e < 8; e++){
      float f = (float)cnt[e] / (float)T_TOK;
      float P = sm[e] / (float)T_TOK;
      a += f * P;
    }
    aux_out[0] = 0.01f * (float)NEXP * a;
  }
}

// Grouped GEMM, 256x128 tile, 8 waves (4M x 2N; each wave = m97 64x64/acc4x4),
// BK=64, single 48KB LDS (As 32K + Bs 16K), glds-A (gathered bf16 rows) +
// reg-staged fp32 B (T14, no cvt pass needed), 2 barriers/K-step.
// lb(512,6) -> 3 blocks/CU (24 waves/CU, LDS 144KB, VGPR cap 85; R14 compiled
// to 84): the 3-blocks/CU shape is the prerequisite for the ~5.5 TB/s per-CU
// staged-byte rate (R8 vs R10/R14); BM=256 halves fp32-B re-staging ->
// 524 MB staged per GEMM ≈ 100us at rate.
// bid = (sk*MAXT + t)*NT + nt; block scans cnt[] to decode t -> (e, mt).
// PHASE2=false: A=xb, B=w1 -> h = gelu(acc+b1) bf16
// PHASE2=true : A=h,  B=w2 -> PART[sk][tok][col] = acc (+b2 if sk==0) fp32
template<int ASTR, int BSTR, int NTOT, int NT, int KS, bool PHASE2>
__global__ __launch_bounds__(512, 6) void ffn_gemm(
    const u16*  __restrict__ Aall,
    const float* __restrict__ Bf,    // fp32 weights [E][NTOT][BSTR]
    const float* __restrict__ bias,
    const int*  __restrict__ cnt,
    const int*  __restrict__ list,
    u16*  __restrict__ hOut,
    float* __restrict__ pOut)
{
  int bid = blockIdx.x;
  int nt = bid % NT;
  int r1 = bid / NT;
  int t  = r1 % MAXT;
  int sk = r1 / MAXT;

  // decode compacted tile index -> (e, mt)   (256-row tiles)
  int e = -1, mt = 0, accT = 0;
  #pragma unroll
  for (int i = 0; i < NEXP; i++){
    int nti = (cnt[i] + 255) >> 8;
    if (e < 0 && t < accT + nti){ e = i; mt = t - accT; }
    accT += nti;
  }
  if (e < 0) return;
  int ne = cnt[e];
  int m0 = mt * 256;
  const int* lst = list + e * T_TOK;
  int n0 = nt * 128;
  int koff = sk * (KS * 64);

  __shared__ u16 As[16384];          // [256][64] swizzled, 32KB
  __shared__ u16 Bs[8192];           // [128][64] swizzled, 16KB

  int tid  = threadIdx.x;
  int lane = tid & 63;
  int w    = tid >> 6;               // 8 waves
  int wm = w >> 1, wn = w & 1;       // 4M x 2N; wave out 64x64 (m97 shape)
  int fr = lane & 15, fq = lane >> 4;

  // A staging via glds: 32 segs of 1KB (8 rows x 64 cols); wave owns 4.
  // lane l -> row seg*8+(l>>3); fetches global chunk g=(l&7)^(row&7) so
  // LDS[row][slot] holds global chunk slot^(row&7) (both-sides swizzle).
  const u16* aS[4]; int aDst[4];
  #pragma unroll
  for (int i = 0; i < 4; i++){
    int seg = w * 4 + i;
    int rr  = seg * 8 + (lane >> 3);
    int gg  = (lane & 7) ^ (rr & 7);
    int mrow = m0 + rr; if (mrow > ne - 1) mrow = ne - 1;
    aS[i] = Aall + (size_t)lst[mrow] * ASTR + koff + gg * 8;
    aDst[i] = seg * 512;
  }

  // B reg-staging: 1024 chunks (128 rows x 8 slots of 8 bf16); thread owns 2.
  const float* bS[2]; int bDst[2];
  #pragma unroll
  for (int i = 0; i < 2; i++){
    int cc = i * 512 + tid;
    int rr = cc >> 3, sl = cc & 7;
    int gg = sl ^ (rr & 7);
    bS[i] = Bf + ((size_t)e * NTOT + n0 + rr) * BSTR + koff + gg * 8;
    bDst[i] = rr * 64 + sl * 8;
  }

  f32x4 acc[4][4];
  #pragma unroll
  for (int m = 0; m < 4; m++)
    #pragma unroll
    for (int n = 0; n < 4; n++)
      acc[m][n] = (f32x4){0.f, 0.f, 0.f, 0.f};

  float4 br0[2], br1[2];
  #pragma unroll
  for (int i = 0; i < 2; i++){
    const float4* s = (const float4*)bS[i];
    br0[i] = s[0]; br1[i] = s[1];
  }

  for (int ks = 0; ks < KS; ++ks){
    if (ks) __syncthreads();         // all waves done reading LDS (lgkm drained)
    size_t ko = (size_t)ks * 64;
    #pragma unroll
    for (int i = 0; i < 4; i++) glds16(aS[i] + ko, &As[aDst[i]]);
    // write B(ks) from regs (cvt fp32->bf16, swizzled chunks)
    #pragma unroll
    for (int i = 0; i < 2; i++){
      uint4 pk;
      pk.x = (unsigned)f2bf(br0[i].x) | ((unsigned)f2bf(br0[i].y) << 16);
      pk.y = (unsigned)f2bf(br0[i].z) | ((unsigned)f2bf(br0[i].w) << 16);
      pk.z = (unsigned)f2bf(br1[i].x) | ((unsigned)f2bf(br1[i].y) << 16);
      pk.w = (unsigned)f2bf(br1[i].z) | ((unsigned)f2bf(br1[i].w) << 16);
      *(uint4*)&Bs[bDst[i]] = pk;
    }
    // issue B(ks+1) reg loads; drain at the barrier with glds-A
    if (ks + 1 < KS){
      #pragma unroll
      for (int i = 0; i < 2; i++){
        const float4* s = (const float4*)(bS[i] + (ks + 1) * 64);
        br0[i] = s[0]; br1[i] = s[1];
      }
    }
    __syncthreads();                 // vmcnt(0)+lgkm drain: tile resident
    #pragma unroll
    for (int kc = 0; kc < 2; kc++){
      short8 afr[4], bfr[4];
      #pragma unroll
      for (int m = 0; m < 4; m++){
        int row  = wm * 64 + m * 16 + fr;
        int slot = (kc * 4 + fq) ^ (row & 7);
        afr[m] = *(const short8*)&As[row * 64 + slot * 8];
      }
      #pragma unroll
      for (int n = 0; n < 4; n++){
        int row  = wn * 64 + n * 16 + fr;
        int slot = (kc * 4 + fq) ^ (row & 7);
        bfr[n] = *(const short8*)&Bs[row * 64 + slot * 8];
      }
      #pragma unroll
      for (int m = 0; m < 4; m++)
        #pragma unroll
        for (int n = 0; n < 4; n++)
          acc[m][n] = __builtin_amdgcn_mfma_f32_16x16x32_bf16(afr[m], bfr[n], acc[m][n], 0, 0, 0);
    }
  }

  // epilogue: C frag layout col = lane&15, row = (lane>>4)*4 + i
  #pragma unroll
  for (int n = 0; n < 4; n++){
    int col = n0 + wn * 64 + n * 16 + fr;
    float bv = bias[(size_t)e * NTOT + col];
    if (PHASE2 && sk != 0) bv = 0.f;
    #pragma unroll
    for (int m = 0; m < 4; m++){
      int rbase = m0 + wm * 64 + m * 16 + fq * 4;
      f32x4 v = acc[m][n];
      #pragma unroll
      for (int i = 0; i < 4; i++){
        int mrow = rbase + i;
        if (mrow < ne){
          int tok = lst[mrow];
          float val = v[i] + bv;
          if (PHASE2){
            pOut[((size_t)sk * T_TOK + tok) * DM + col] = val;
          } else {
            float gl = 0.5f * val * (1.0f + erff(val * 0.70710678118654752f));
            hOut[(size_t)tok * HID + col] = f2bf(gl);
          }
        }
      }
    }
  }
}

// out = gate * (part0+part1+part2+part3)   (b2 already in part0)
__global__ __launch_bounds__(256) void reduce_kernel(
    const float* __restrict__ part, const float* __restrict__ gate,
    float* __restrict__ out)
{
  size_t i = (size_t)blockIdx.x * 256 + threadIdx.x;     // float4 index
  constexpr size_t S = (size_t)T_TOK * DM / 4;
  const float4* p = (const float4*)part;
  float4 a = p[i], b = p[i + S], c = p[i + 2 * S], d = p[i + 3 * S];
  float g = gate[i >> 8];                                // 256 float4 per row
  float4 o;
  o.x = (a.x + b.x + c.x + d.x) * g;
  o.y = (a.y + b.y + c.y + d.y) * g;
  o.z = (a.z + b.z + c.z + d.z) * g;
  o.w = (a.w + b.w + c.w + d.w) * g;
  ((float4*)out)[i] = o;
}

extern "C" void kernel_launch(void* const* d_in, const int* in_sizes, int n_in,
                              void* d_out, int out_size, void* d_ws, size_t ws_size,
                              hipStream_t stream) {
  const float* x   = (const float*)d_in[0];
  const float* gw  = (const float*)d_in[1];
  const float* w1  = (const float*)d_in[2];
  const float* b1  = (const float*)d_in[3];
  const float* w2  = (const float*)d_in[4];
  const float* b2  = (const float*)d_in[5];

  char* ws = (char*)d_ws;
  float* gateo = (float*)(ws + GATE_OFF);
  int*   cnt   = (int*)  (ws + CNT_OFF);
  int*   list  = (int*)  (ws + LIST_OFF);
  float* probs = (float*)(ws + PROBS_OFF);
  u16*   xb    = (u16*)  (ws + XB_OFF);
  u16*   h     = (u16*)  (ws + H_OFF);
  float* part  = (float*)(ws + PART_OFF);

  float* out = (float*)d_out;
  float* aux = out + (size_t)T_TOK * DM;

  hipLaunchKernelGGL(zero_cnt_kernel, dim3(1), dim3(64), 0, stream, cnt);
  hipLaunchKernelGGL(gate_kernel, dim3(T_TOK / 4), dim3(256), 0, stream,
                     x, gw, gateo, cnt, list, probs, xb);
  hipLaunchKernelGGL(aux_kernel, dim3(1), dim3(256), 0, stream, probs, cnt, aux);

  // GEMM1: xb[tok,1024] x w1[e][4096][1024] -> h[tok][4096]
  //   ASTR=1024, BSTR=1024, NTOT=4096, NT=32, KS=16, grid = 23*32 = 736
  hipLaunchKernelGGL((ffn_gemm<DM, DM, HID, 32, 16, false>),
                     dim3(MAXT * 32), dim3(512), 0, stream,
                     xb, w1, b1, cnt, list, h, (float*)nullptr);
  // GEMM2: h[tok,4096] x w2[e][1024][4096] -> PART[sk][tok][1024], split-K=4
  //   ASTR=4096, BSTR=4096, NTOT=1024, NT=8, KS=16, grid = 4*23*8 = 736
  hipLaunchKernelGGL((ffn_gemm<HID, HID, DM, 8, 16, true>),
                     dim3(4 * MAXT * 8), dim3(512), 0, stream,
                     h, w2, b2, cnt, list, (u16*)nullptr, part);
  hipLaunchKernelGGL(reduce_kernel, dim3(T_TOK * DM / 4 / 256), dim3(256), 0, stream,
                     part, gateo, out);
}

// Round 21
// 300.872 us; speedup vs baseline: 3.6871x; 3.6871x over previous
//
#include <hip/hip_runtime.h>
#include <math.h>

#define T_TOK 4096
#define DM 1024
#define HID 4096
#define NEXP 8
#define MAXT 39   // max total 128-row tiles: 4096/128 + 7
#define NG1  1248 // GEMM1 matmul blocks; cvt-w2 tail = bids [NG1, NG1+512)

typedef unsigned short u16;
typedef __attribute__((ext_vector_type(8))) short short8;
typedef __attribute__((ext_vector_type(4))) float f32x4;

__device__ __forceinline__ u16 f2bf(float f){
  unsigned u = __float_as_uint(f);
  u += 0x7FFF + ((u >> 16) & 1);
  return (u16)(u >> 16);
}

// ---- workspace layout (byte offsets) ----
#define GATE_OFF   0u          // float[4096]
#define CNT_OFF    16384u      // int[8]
#define LIST_OFF   16512u      // int[8][4096]
#define PROBS_OFF  147584u     // float[4096][8]
#define XB_OFF     278656u     // bf16[4096][1024]
#define H_OFF      8667264u    // bf16[4096][4096]
#define W1B_OFF    42221696u   // bf16[8][4096][1024] = 67MB (dead after GEMM1)
#define PART_OFF   W1B_OFF     // float[4][4096][1024] = 67MB, overlays w1b
#define W2B_OFF    109330560u  // bf16[8][1024][4096] = 67MB

__device__ __forceinline__ void glds16(const void* g, void* l){
  __builtin_amdgcn_global_load_lds((const __attribute__((address_space(1))) void*)g,
                                   (__attribute__((address_space(3))) void*)l, 16, 0, 0);
}

__global__ void zero_cnt_kernel(int* cnt){
  if (threadIdx.x < NEXP) cnt[threadIdx.x] = 0;
}

// gate (blocks [0,1024)) FUSED with cvt-w1 tail (blocks [1024,1536)).
// gate: one wave per token (gating + routing + x->bf16). cvt: grid-stride
// fp32->bf16, 32B read / 16B write per lane-iter (R16's proven ~4.5TB/s form).
__global__ __launch_bounds__(256) void gate_kernel(
    const float* __restrict__ x, const float* __restrict__ gw,
    float* __restrict__ gateo, int* __restrict__ cnt, int* __restrict__ list,
    float* __restrict__ probs, u16* __restrict__ xb,
    const float* __restrict__ w1, u16* __restrict__ w1b)
{
  int tid = threadIdx.x;
  if (blockIdx.x >= 1024){
    const size_t TOT = (size_t)NEXP * HID * DM / 8;      // 4,194,304 groups
    size_t stride = (size_t)512 * 256;
    for (size_t g = (size_t)(blockIdx.x - 1024) * 256 + tid; g < TOT; g += stride){
      const float4* s = (const float4*)w1 + g * 2;
      float4 a = s[0], c = s[1];
      uint4 p;
      p.x = (unsigned)f2bf(a.x) | ((unsigned)f2bf(a.y) << 16);
      p.y = (unsigned)f2bf(a.z) | ((unsigned)f2bf(a.w) << 16);
      p.z = (unsigned)f2bf(c.x) | ((unsigned)f2bf(c.y) << 16);
      p.w = (unsigned)f2bf(c.z) | ((unsigned)f2bf(c.w) << 16);
      ((uint4*)w1b)[g] = p;
    }
    return;
  }

  int lane = tid & 63;
  int w = tid >> 6;
  int t = blockIdx.x * 4 + w;

  const float4* x4 = (const float4*)(x + (size_t)t * DM);
  const float4* g4 = (const float4*)gw;

  float acc[8] = {0,0,0,0,0,0,0,0};
  #pragma unroll
  for (int i = 0; i < 4; i++){
    int p = i * 64 + lane;
    float4 xv = x4[p];
    ushort4 pk;
    pk.x = f2bf(xv.x); pk.y = f2bf(xv.y); pk.z = f2bf(xv.z); pk.w = f2bf(xv.w);
    *(ushort4*)&xb[(size_t)t * DM + (size_t)p * 4] = pk;
    #pragma unroll
    for (int e = 0; e < NEXP; e++){
      float4 gv = g4[e * 256 + p];
      acc[e] += xv.x * gv.x + xv.y * gv.y + xv.z * gv.z + xv.w * gv.w;
    }
  }
  #pragma unroll
  for (int e = 0; e < NEXP; e++){
    #pragma unroll
    for (int off = 32; off; off >>= 1)
      acc[e] += __shfl_xor(acc[e], off);
  }
  if (lane == 0){
    float mx = acc[0];
    #pragma unroll
    for (int e = 1; e < NEXP; e++) mx = fmaxf(mx, acc[e]);
    float p[8]; float s = 0.f;
    #pragma unroll
    for (int e = 0; e < NEXP; e++){ p[e] = expf(acc[e] - mx); s += p[e]; }
    float inv = 1.f / s;
    int be = 0; float bp = p[0];
    #pragma unroll
    for (int e = 1; e < NEXP; e++){ if (p[e] > bp){ bp = p[e]; be = e; } }
    #pragma unroll
    for (int e = 0; e < NEXP; e++) probs[(size_t)t * 8 + e] = p[e] * inv;
    gateo[t] = bp * inv;
    int pos = atomicAdd(&cnt[be], 1);
    list[be * T_TOK + pos] = t;
  }
}

// deterministic aux-loss reduction, one block
__global__ __launch_bounds__(256) void aux_kernel(
    const float* __restrict__ probs, const int* __restrict__ cnt,
    float* __restrict__ aux_out)
{
  __shared__ float sm[256 * 8];
  int tid = threadIdx.x;
  float s[8] = {0,0,0,0,0,0,0,0};
  for (int i = 0; i < 16; i++){
    int t = i * 256 + tid;
    #pragma unroll
    for (int e = 0; e < 8; e++) s[e] += probs[(size_t)t * 8 + e];
  }
  #pragma unroll
  for (int e = 0; e < 8; e++) sm[tid * 8 + e] = s[e];
  __syncthreads();
  for (int st = 128; st; st >>= 1){
    if (tid < st){
      #pragma unroll
      for (int e = 0; e < 8; e++) sm[tid * 8 + e] += sm[(tid + st) * 8 + e];
    }
    __syncthreads();
  }
  if (tid == 0){
    float a = 0.f;
    #pragma unroll
    for (int e = 0; e < 8; e++){
      float f = (float)cnt[e] / (float)T_TOK;
      float P = sm[e] / (float)T_TOK;
      a += f * P;
    }
    aux_out[0] = 0.01f * (float)NEXP * a;
  }
}

// GEMM1, R16-exact bf16 path (measured 93us floor: 128x128, BK=64, 4 waves,
// single 32KB LDS, glds-direct bf16 both operands, lb(256,3) = 3 blocks/CU),
// FUSED with cvt-w2 tail blocks [NG1, NG1+512) (R19's proven fusion: GEMM1 is
// glds-supply-bound at ~17% HBM, so cvt's buffer traffic hides in its shadow).
__global__ __launch_bounds__(256, 3) void ffn_gemm1(
    const u16*  __restrict__ Aall,   // xb bf16 [4096][1024]
    const u16*  __restrict__ Bb,     // w1b bf16 [E][4096][1024]
    const float* __restrict__ bias,  // b1
    const int*  __restrict__ cnt,
    const int*  __restrict__ list,
    u16*  __restrict__ hOut,
    const float* __restrict__ w2,    // cvt src
    u16*  __restrict__ w2b)          // cvt dst
{
  int bid = blockIdx.x;
  int tid = threadIdx.x;

  if (bid >= NG1){
    const size_t TOT = (size_t)NEXP * DM * HID / 8;
    size_t stride = (size_t)512 * 256;
    for (size_t g = (size_t)(bid - NG1) * 256 + tid; g < TOT; g += stride){
      const float4* s = (const float4*)w2 + g * 2;
      float4 a = s[0], c = s[1];
      uint4 p;
      p.x = (unsigned)f2bf(a.x) | ((unsigned)f2bf(a.y) << 16);
      p.y = (unsigned)f2bf(a.z) | ((unsigned)f2bf(a.w) << 16);
      p.z = (unsigned)f2bf(c.x) | ((unsigned)f2bf(c.y) << 16);
      p.w = (unsigned)f2bf(c.z) | ((unsigned)f2bf(c.w) << 16);
      ((uint4*)w2b)[g] = p;
    }
    return;
  }

  constexpr int NT = 32, KS = 16;
  int nt = bid % NT;
  int t  = bid / NT;

  int e = -1, mt = 0, accT = 0;
  #pragma unroll
  for (int i = 0; i < NEXP; i++){
    int nti = (cnt[i] + 127) >> 7;
    if (e < 0 && t < accT + nti){ e = i; mt = t - accT; }
    accT += nti;
  }
  if (e < 0) return;
  int ne = cnt[e];
  int m0 = mt * 128;
  const int* lst = list + e * T_TOK;
  int n0 = nt * 128;

  __shared__ u16 As[8192];           // [128][64] swizzled, 16KB
  __shared__ u16 Bs[8192];

  int lane = tid & 63;
  int w    = tid >> 6;               // 4 waves
  int wm = w >> 1, wn = w & 1;       // 2M x 2N; wave out 64x64
  int fr = lane & 15, fq = lane >> 4;

  const u16* aS[4]; const u16* bS[4]; int dst[4];
  #pragma unroll
  for (int i = 0; i < 4; i++){
    int seg = w * 4 + i;
    int r   = seg * 8 + (lane >> 3);
    int g   = (lane & 7) ^ (r & 7);
    int mrow = m0 + r; if (mrow > ne - 1) mrow = ne - 1;
    aS[i] = Aall + (size_t)lst[mrow] * DM + g * 8;
    bS[i] = Bb + (size_t)e * HID * DM + (size_t)(n0 + r) * DM + g * 8;
    dst[i] = seg * 512;
  }

  f32x4 acc[4][4];
  #pragma unroll
  for (int m = 0; m < 4; m++)
    #pragma unroll
    for (int n = 0; n < 4; n++)
      acc[m][n] = (f32x4){0.f, 0.f, 0.f, 0.f};

  for (int ks = 0; ks < KS; ++ks){
    if (ks) __syncthreads();
    size_t ko = (size_t)ks * 64;
    #pragma unroll
    for (int i = 0; i < 4; i++) glds16(aS[i] + ko, &As[dst[i]]);
    #pragma unroll
    for (int i = 0; i < 4; i++) glds16(bS[i] + ko, &Bs[dst[i]]);
    __syncthreads();
    #pragma unroll
    for (int kc = 0; kc < 2; kc++){
      short8 afr[4], bfr[4];
      #pragma unroll
      for (int m = 0; m < 4; m++){
        int row  = wm * 64 + m * 16 + fr;
        int slot = (kc * 4 + fq) ^ (row & 7);
        afr[m] = *(const short8*)&As[row * 64 + slot * 8];
      }
      #pragma unroll
      for (int n = 0; n < 4; n++){
        int row  = wn * 64 + n * 16 + fr;
        int slot = (kc * 4 + fq) ^ (row & 7);
        bfr[n] = *(const short8*)&Bs[row * 64 + slot * 8];
      }
      #pragma unroll
      for (int m = 0; m < 4; m++)
        #pragma unroll
        for (int n = 0; n < 4; n++)
          acc[m][n] = __builtin_amdgcn_mfma_f32_16x16x32_bf16(afr[m], bfr[n], acc[m][n], 0, 0, 0);
    }
  }

  #pragma unroll
  for (int n = 0; n < 4; n++){
    int col = n0 + wn * 64 + n * 16 + fr;
    float bv = bias[(size_t)e * HID + col];
    #pragma unroll
    for (int m = 0; m < 4; m++){
      int rbase = m0 + wm * 64 + m * 16 + fq * 4;
      f32x4 v = acc[m][n];
      #pragma unroll
      for (int i = 0; i < 4; i++){
        int mrow = rbase + i;
        if (mrow < ne){
          int tok = lst[mrow];
          float val = v[i] + bv;
          float gl = 0.5f * val * (1.0f + erff(val * 0.70710678118654752f));
          hOut[(size_t)tok * HID + col] = f2bf(gl);
        }
      }
    }
  }
}

// GEMM2, R16/R19-exact bf16 path: 128x128, BK=64, 4 waves, single 32KB LDS,
// glds-direct bf16 both operands, lb(256,3), split-K=4 -> PART.
__global__ __launch_bounds__(256, 3) void ffn_gemm2(
    const u16*  __restrict__ Aall,   // h bf16 [4096][4096]
    const u16*  __restrict__ Bb,     // w2b bf16 [E][1024][4096]
    const float* __restrict__ bias,  // b2
    const int*  __restrict__ cnt,
    const int*  __restrict__ list,
    float* __restrict__ pOut)        // PART [4][4096][1024]
{
  constexpr int NT = 8, KS = 16;
  int bid = blockIdx.x;
  int nt = bid % NT;
  int r1 = bid / NT;
  int t  = r1 % MAXT;
  int sk = r1 / MAXT;

  int e = -1, mt = 0, accT = 0;
  #pragma unroll
  for (int i = 0; i < NEXP; i++){
    int nti = (cnt[i] + 127) >> 7;
    if (e < 0 && t < accT + nti){ e = i; mt = t - accT; }
    accT += nti;
  }
  if (e < 0) return;
  int ne = cnt[e];
  int m0 = mt * 128;
  const int* lst = list + e * T_TOK;
  int n0 = nt * 128;
  int koff = sk * (KS * 64);

  __shared__ u16 As[8192];
  __shared__ u16 Bs[8192];

  int tid  = threadIdx.x;
  int lane = tid & 63;
  int w    = tid >> 6;
  int wm = w >> 1, wn = w & 1;
  int fr = lane & 15, fq = lane >> 4;

  const u16* aS[4]; const u16* bS[4]; int dst[4];
  #pragma unroll
  for (int i = 0; i < 4; i++){
    int seg = w * 4 + i;
    int r   = seg * 8 + (lane >> 3);
    int g   = (lane & 7) ^ (r & 7);
    int mrow = m0 + r; if (mrow > ne - 1) mrow = ne - 1;
    aS[i] = Aall + (size_t)lst[mrow] * HID + koff + g * 8;
    bS[i] = Bb + (size_t)e * DM * HID + (size_t)(n0 + r) * HID + koff + g * 8;
    dst[i] = seg * 512;
  }

  f32x4 acc[4][4];
  #pragma unroll
  for (int m = 0; m < 4; m++)
    #pragma unroll
    for (int n = 0; n < 4; n++)
      acc[m][n] = (f32x4){0.f, 0.f, 0.f, 0.f};

  for (int ks = 0; ks < KS; ++ks){
    if (ks) __syncthreads();
    size_t ko = (size_t)ks * 64;
    #pragma unroll
    for (int i = 0; i < 4; i++) glds16(aS[i] + ko, &As[dst[i]]);
    #pragma unroll
    for (int i = 0; i < 4; i++) glds16(bS[i] + ko, &Bs[dst[i]]);
    __syncthreads();
    #pragma unroll
    for (int kc = 0; kc < 2; kc++){
      short8 afr[4], bfr[4];
      #pragma unroll
      for (int m = 0; m < 4; m++){
        int row  = wm * 64 + m * 16 + fr;
        int slot = (kc * 4 + fq) ^ (row & 7);
        afr[m] = *(const short8*)&As[row * 64 + slot * 8];
      }
      #pragma unroll
      for (int n = 0; n < 4; n++){
        int row  = wn * 64 + n * 16 + fr;
        int slot = (kc * 4 + fq) ^ (row & 7);
        bfr[n] = *(const short8*)&Bs[row * 64 + slot * 8];
      }
      #pragma unroll
      for (int m = 0; m < 4; m++)
        #pragma unroll
        for (int n = 0; n < 4; n++)
          acc[m][n] = __builtin_amdgcn_mfma_f32_16x16x32_bf16(afr[m], bfr[n], acc[m][n], 0, 0, 0);
    }
  }

  #pragma unroll
  for (int n = 0; n < 4; n++){
    int col = n0 + wn * 64 + n * 16 + fr;
    float bv = (sk == 0) ? bias[(size_t)e * DM + col] : 0.f;
    #pragma unroll
    for (int m = 0; m < 4; m++){
      int rbase = m0 + wm * 64 + m * 16 + fq * 4;
      f32x4 v = acc[m][n];
      #pragma unroll
      for (int i = 0; i < 4; i++){
        int mrow = rbase + i;
        if (mrow < ne){
          int tok = lst[mrow];
          pOut[((size_t)sk * T_TOK + tok) * DM + col] = v[i] + bv;
        }
      }
    }
  }
}

// out = gate * (part0+part1+part2+part3)   (b2 already in part0)
__global__ __launch_bounds__(256) void reduce_kernel(
    const float* __restrict__ part, const float* __restrict__ gate,
    float* __restrict__ out)
{
  size_t i = (size_t)blockIdx.x * 256 + threadIdx.x;
  constexpr size_t S = (size_t)T_TOK * DM / 4;
  const float4* p = (const float4*)part;
  float4 a = p[i], b = p[i + S], c = p[i + 2 * S], d = p[i + 3 * S];
  float g = gate[i >> 8];
  float4 o;
  o.x = (a.x + b.x + c.x + d.x) * g;
  o.y = (a.y + b.y + c.y + d.y) * g;
  o.z = (a.z + b.z + c.z + d.z) * g;
  o.w = (a.w + b.w + c.w + d.w) * g;
  ((float4*)out)[i] = o;
}

extern "C" void kernel_launch(void* const* d_in, const int* in_sizes, int n_in,
                              void* d_out, int out_size, void* d_ws, size_t ws_size,
                              hipStream_t stream) {
  const float* x   = (const float*)d_in[0];
  const float* gw  = (const float*)d_in[1];
  const float* w1  = (const float*)d_in[2];
  const float* b1  = (const float*)d_in[3];
  const float* w2  = (const float*)d_in[4];
  const float* b2  = (const float*)d_in[5];

  char* ws = (char*)d_ws;
  float* gateo = (float*)(ws + GATE_OFF);
  int*   cnt   = (int*)  (ws + CNT_OFF);
  int*   list  = (int*)  (ws + LIST_OFF);
  float* probs = (float*)(ws + PROBS_OFF);
  u16*   xb    = (u16*)  (ws + XB_OFF);
  u16*   h     = (u16*)  (ws + H_OFF);
  u16*   w1b   = (u16*)  (ws + W1B_OFF);
  float* part  = (float*)(ws + PART_OFF);   // overlays w1b (dead after GEMM1)
  u16*   w2b   = (u16*)  (ws + W2B_OFF);

  float* out = (float*)d_out;
  float* aux = out + (size_t)T_TOK * DM;

  hipLaunchKernelGGL(zero_cnt_kernel, dim3(1), dim3(64), 0, stream, cnt);
  // gate (1024 blocks) fused with cvt-w1 tail (512 blocks)
  hipLaunchKernelGGL(gate_kernel, dim3(1536), dim3(256), 0, stream,
                     x, gw, gateo, cnt, list, probs, xb, w1, w1b);
  hipLaunchKernelGGL(aux_kernel, dim3(1), dim3(256), 0, stream, probs, cnt, aux);

  // GEMM1 (bf16 w1b) fused with cvt-w2 tail blocks
  hipLaunchKernelGGL(ffn_gemm1, dim3(NG1 + 512), dim3(256), 0, stream,
                     xb, w1b, b1, cnt, list, h, w2, w2b);
  // GEMM2 (bf16 w2b), split-K=4 -> PART
  hipLaunchKernelGGL(ffn_gemm2, dim3(4 * MAXT * 8), dim3(256), 0, stream,
                     h, w2b, b2, cnt, list, part);
  hipLaunchKernelGGL(reduce_kernel, dim3(T_TOK * DM / 4 / 256), dim3(256), 0, stream,
                     part, gateo, out);
}

// Round 22
// 299.259 us; speedup vs baseline: 3.7069x; 1.0054x over previous
//
#include <hip/hip_runtime.h>
#include <math.h>

#define T_TOK 4096
#define DM 1024
#define HID 4096
#define NEXP 8
#define MAXT 39   // max total 128-row tiles: 4096/128 + 7
#define NG1  1248 // GEMM1 matmul blocks; cvt-w2 tail = bids [NG1, NG1+512)

typedef unsigned short u16;
typedef __attribute__((ext_vector_type(8))) short short8;
typedef __attribute__((ext_vector_type(4))) float f32x4;

__device__ __forceinline__ u16 f2bf(float f){
  unsigned u = __float_as_uint(f);
  u += 0x7FFF + ((u >> 16) & 1);
  return (u16)(u >> 16);
}

// ---- workspace layout (byte offsets) ----
#define GATE_OFF   0u          // float[4096]
#define CNT_OFF    16384u      // int[8]
#define LIST_OFF   16512u      // int[8][4096]
#define PROBS_OFF  147584u     // float[4096][8]
#define XB_OFF     278656u     // bf16[4096][1024]
#define H_OFF      8667264u    // bf16[4096][4096]
#define W1B_OFF    42221696u   // bf16[8][4096][1024] = 67MB (dead after GEMM1)
#define PART_OFF   W1B_OFF     // float[4][4096][1024] = 67MB, overlays w1b
#define W2B_OFF    109330560u  // bf16[8][1024][4096] = 67MB

__device__ __forceinline__ void glds16(const void* g, void* l){
  __builtin_amdgcn_global_load_lds((const __attribute__((address_space(1))) void*)g,
                                   (__attribute__((address_space(3))) void*)l, 16, 0, 0);
}

__global__ void zero_cnt_kernel(int* cnt){
  if (threadIdx.x < NEXP) cnt[threadIdx.x] = 0;
}

// gate (blocks [0,1024)) FUSED with cvt-w1 tail (blocks [1024,3072) = 2048
// blocks; R21's 512-block tail ran at only 3.5 TB/s -> 112us; 2048 blocks is
// the G11 streaming sweet spot). cvt: grid-stride fp32->bf16, 32B read /
// 16B write per lane-iter. Side effect: w1b is L3-hot when GEMM1 stages it
// (R21 discovery: GEMM1-fused dropped to ~76us on hot w1b).
__global__ __launch_bounds__(256) void gate_kernel(
    const float* __restrict__ x, const float* __restrict__ gw,
    float* __restrict__ gateo, int* __restrict__ cnt, int* __restrict__ list,
    float* __restrict__ probs, u16* __restrict__ xb,
    const float* __restrict__ w1, u16* __restrict__ w1b)
{
  int tid = threadIdx.x;
  if (blockIdx.x >= 1024){
    const size_t TOT = (size_t)NEXP * HID * DM / 8;      // 4,194,304 groups
    size_t stride = (size_t)2048 * 256;
    for (size_t g = (size_t)(blockIdx.x - 1024) * 256 + tid; g < TOT; g += stride){
      const float4* s = (const float4*)w1 + g * 2;
      float4 a = s[0], c = s[1];
      uint4 p;
      p.x = (unsigned)f2bf(a.x) | ((unsigned)f2bf(a.y) << 16);
      p.y = (unsigned)f2bf(a.z) | ((unsigned)f2bf(a.w) << 16);
      p.z = (unsigned)f2bf(c.x) | ((unsigned)f2bf(c.y) << 16);
      p.w = (unsigned)f2bf(c.z) | ((unsigned)f2bf(c.w) << 16);
      ((uint4*)w1b)[g] = p;
    }
    return;
  }

  int lane = tid & 63;
  int w = tid >> 6;
  int t = blockIdx.x * 4 + w;

  const float4* x4 = (const float4*)(x + (size_t)t * DM);
  const float4* g4 = (const float4*)gw;

  float acc[8] = {0,0,0,0,0,0,0,0};
  #pragma unroll
  for (int i = 0; i < 4; i++){
    int p = i * 64 + lane;
    float4 xv = x4[p];
    ushort4 pk;
    pk.x = f2bf(xv.x); pk.y = f2bf(xv.y); pk.z = f2bf(xv.z); pk.w = f2bf(xv.w);
    *(ushort4*)&xb[(size_t)t * DM + (size_t)p * 4] = pk;
    #pragma unroll
    for (int e = 0; e < NEXP; e++){
      float4 gv = g4[e * 256 + p];
      acc[e] += xv.x * gv.x + xv.y * gv.y + xv.z * gv.z + xv.w * gv.w;
    }
  }
  #pragma unroll
  for (int e = 0; e < NEXP; e++){
    #pragma unroll
    for (int off = 32; off; off >>= 1)
      acc[e] += __shfl_xor(acc[e], off);
  }
  if (lane == 0){
    float mx = acc[0];
    #pragma unroll
    for (int e = 1; e < NEXP; e++) mx = fmaxf(mx, acc[e]);
    float p[8]; float s = 0.f;
    #pragma unroll
    for (int e = 0; e < NEXP; e++){ p[e] = expf(acc[e] - mx); s += p[e]; }
    float inv = 1.f / s;
    int be = 0; float bp = p[0];
    #pragma unroll
    for (int e = 1; e < NEXP; e++){ if (p[e] > bp){ bp = p[e]; be = e; } }
    #pragma unroll
    for (int e = 0; e < NEXP; e++) probs[(size_t)t * 8 + e] = p[e] * inv;
    gateo[t] = bp * inv;
    int pos = atomicAdd(&cnt[be], 1);
    list[be * T_TOK + pos] = t;
  }
}

// deterministic aux-loss reduction, one block
__global__ __launch_bounds__(256) void aux_kernel(
    const float* __restrict__ probs, const int* __restrict__ cnt,
    float* __restrict__ aux_out)
{
  __shared__ float sm[256 * 8];
  int tid = threadIdx.x;
  float s[8] = {0,0,0,0,0,0,0,0};
  for (int i = 0; i < 16; i++){
    int t = i * 256 + tid;
    #pragma unroll
    for (int e = 0; e < 8; e++) s[e] += probs[(size_t)t * 8 + e];
  }
  #pragma unroll
  for (int e = 0; e < 8; e++) sm[tid * 8 + e] = s[e];
  __syncthreads();
  for (int st = 128; st; st >>= 1){
    if (tid < st){
      #pragma unroll
      for (int e = 0; e < 8; e++) sm[tid * 8 + e] += sm[(tid + st) * 8 + e];
    }
    __syncthreads();
  }
  if (tid == 0){
    float a = 0.f;
    #pragma unroll
    for (int e = 0; e < 8; e++){
      float f = (float)cnt[e] / (float)T_TOK;
      float P = sm[e] / (float)T_TOK;
      a += f * P;
    }
    aux_out[0] = 0.01f * (float)NEXP * a;
  }
}

// GEMM1, R16-exact bf16 path (128x128, BK=64, 4 waves, single 32KB LDS,
// glds-direct bf16 both operands, lb(256,3) = 3 blocks/CU), FUSED with
// cvt-w2 tail blocks [NG1, NG1+512) (R19/R21-proven: GEMM1 is supply-bound
// at ~17% HBM, cvt traffic hides in its shadow; w1b is L3-hot from gate's cvt).
__global__ __launch_bounds__(256, 3) void ffn_gemm1(
    const u16*  __restrict__ Aall,   // xb bf16 [4096][1024]
    const u16*  __restrict__ Bb,     // w1b bf16 [E][4096][1024]
    const float* __restrict__ bias,  // b1
    const int*  __restrict__ cnt,
    const int*  __restrict__ list,
    u16*  __restrict__ hOut,
    const float* __restrict__ w2,    // cvt src
    u16*  __restrict__ w2b)          // cvt dst
{
  int bid = blockIdx.x;
  int tid = threadIdx.x;

  if (bid >= NG1){
    const size_t TOT = (size_t)NEXP * DM * HID / 8;
    size_t stride = (size_t)512 * 256;
    for (size_t g = (size_t)(bid - NG1) * 256 + tid; g < TOT; g += stride){
      const float4* s = (const float4*)w2 + g * 2;
      float4 a = s[0], c = s[1];
      uint4 p;
      p.x = (unsigned)f2bf(a.x) | ((unsigned)f2bf(a.y) << 16);
      p.y = (unsigned)f2bf(a.z) | ((unsigned)f2bf(a.w) << 16);
      p.z = (unsigned)f2bf(c.x) | ((unsigned)f2bf(c.y) << 16);
      p.w = (unsigned)f2bf(c.z) | ((unsigned)f2bf(c.w) << 16);
      ((uint4*)w2b)[g] = p;
    }
    return;
  }

  constexpr int NT = 32, KS = 16;
  int nt = bid % NT;
  int t  = bid / NT;

  int e = -1, mt = 0, accT = 0;
  #pragma unroll
  for (int i = 0; i < NEXP; i++){
    int nti = (cnt[i] + 127) >> 7;
    if (e < 0 && t < accT + nti){ e = i; mt = t - accT; }
    accT += nti;
  }
  if (e < 0) return;
  int ne = cnt[e];
  int m0 = mt * 128;
  const int* lst = list + e * T_TOK;
  int n0 = nt * 128;

  __shared__ u16 As[8192];           // [128][64] swizzled, 16KB
  __shared__ u16 Bs[8192];

  int lane = tid & 63;
  int w    = tid >> 6;               // 4 waves
  int wm = w >> 1, wn = w & 1;       // 2M x 2N; wave out 64x64
  int fr = lane & 15, fq = lane >> 4;

  const u16* aS[4]; const u16* bS[4]; int dst[4];
  #pragma unroll
  for (int i = 0; i < 4; i++){
    int seg = w * 4 + i;
    int r   = seg * 8 + (lane >> 3);
    int g   = (lane & 7) ^ (r & 7);
    int mrow = m0 + r; if (mrow > ne - 1) mrow = ne - 1;
    aS[i] = Aall + (size_t)lst[mrow] * DM + g * 8;
    bS[i] = Bb + (size_t)e * HID * DM + (size_t)(n0 + r) * DM + g * 8;
    dst[i] = seg * 512;
  }

  f32x4 acc[4][4];
  #pragma unroll
  for (int m = 0; m < 4; m++)
    #pragma unroll
    for (int n = 0; n < 4; n++)
      acc[m][n] = (f32x4){0.f, 0.f, 0.f, 0.f};

  for (int ks = 0; ks < KS; ++ks){
    if (ks) __syncthreads();
    size_t ko = (size_t)ks * 64;
    #pragma unroll
    for (int i = 0; i < 4; i++) glds16(aS[i] + ko, &As[dst[i]]);
    #pragma unroll
    for (int i = 0; i < 4; i++) glds16(bS[i] + ko, &Bs[dst[i]]);
    __syncthreads();
    #pragma unroll
    for (int kc = 0; kc < 2; kc++){
      short8 afr[4], bfr[4];
      #pragma unroll
      for (int m = 0; m < 4; m++){
        int row  = wm * 64 + m * 16 + fr;
        int slot = (kc * 4 + fq) ^ (row & 7);
        afr[m] = *(const short8*)&As[row * 64 + slot * 8];
      }
      #pragma unroll
      for (int n = 0; n < 4; n++){
        int row  = wn * 64 + n * 16 + fr;
        int slot = (kc * 4 + fq) ^ (row & 7);
        bfr[n] = *(const short8*)&Bs[row * 64 + slot * 8];
      }
      #pragma unroll
      for (int m = 0; m < 4; m++)
        #pragma unroll
        for (int n = 0; n < 4; n++)
          acc[m][n] = __builtin_amdgcn_mfma_f32_16x16x32_bf16(afr[m], bfr[n], acc[m][n], 0, 0, 0);
    }
  }

  #pragma unroll
  for (int n = 0; n < 4; n++){
    int col = n0 + wn * 64 + n * 16 + fr;
    float bv = bias[(size_t)e * HID + col];
    #pragma unroll
    for (int m = 0; m < 4; m++){
      int rbase = m0 + wm * 64 + m * 16 + fq * 4;
      f32x4 v = acc[m][n];
      #pragma unroll
      for (int i = 0; i < 4; i++){
        int mrow = rbase + i;
        if (mrow < ne){
          int tok = lst[mrow];
          float val = v[i] + bv;
          float gl = 0.5f * val * (1.0f + erff(val * 0.70710678118654752f));
          hOut[(size_t)tok * HID + col] = f2bf(gl);
        }
      }
    }
  }
}

// GEMM2, R16/R19-exact bf16 path: 128x128, BK=64, 4 waves, single 32KB LDS,
// glds-direct bf16 both operands, lb(256,3), split-K=4 -> PART.
__global__ __launch_bounds__(256, 3) void ffn_gemm2(
    const u16*  __restrict__ Aall,   // h bf16 [4096][4096]
    const u16*  __restrict__ Bb,     // w2b bf16 [E][1024][4096]
    const float* __restrict__ bias,  // b2
    const int*  __restrict__ cnt,
    const int*  __restrict__ list,
    float* __restrict__ pOut)        // PART [4][4096][1024]
{
  constexpr int NT = 8, KS = 16;
  int bid = blockIdx.x;
  int nt = bid % NT;
  int r1 = bid / NT;
  int t  = r1 % MAXT;
  int sk = r1 / MAXT;

  int e = -1, mt = 0, accT = 0;
  #pragma unroll
  for (int i = 0; i < NEXP; i++){
    int nti = (cnt[i] + 127) >> 7;
    if (e < 0 && t < accT + nti){ e = i; mt = t - accT; }
    accT += nti;
  }
  if (e < 0) return;
  int ne = cnt[e];
  int m0 = mt * 128;
  const int* lst = list + e * T_TOK;
  int n0 = nt * 128;
  int koff = sk * (KS * 64);

  __shared__ u16 As[8192];
  __shared__ u16 Bs[8192];

  int tid  = threadIdx.x;
  int lane = tid & 63;
  int w    = tid >> 6;
  int wm = w >> 1, wn = w & 1;
  int fr = lane & 15, fq = lane >> 4;

  const u16* aS[4]; const u16* bS[4]; int dst[4];
  #pragma unroll
  for (int i = 0; i < 4; i++){
    int seg = w * 4 + i;
    int r   = seg * 8 + (lane >> 3);
    int g   = (lane & 7) ^ (r & 7);
    int mrow = m0 + r; if (mrow > ne - 1) mrow = ne - 1;
    aS[i] = Aall + (size_t)lst[mrow] * HID + koff + g * 8;
    bS[i] = Bb + (size_t)e * DM * HID + (size_t)(n0 + r) * HID + koff + g * 8;
    dst[i] = seg * 512;
  }

  f32x4 acc[4][4];
  #pragma unroll
  for (int m = 0; m < 4; m++)
    #pragma unroll
    for (int n = 0; n < 4; n++)
      acc[m][n] = (f32x4){0.f, 0.f, 0.f, 0.f};

  for (int ks = 0; ks < KS; ++ks){
    if (ks) __syncthreads();
    size_t ko = (size_t)ks * 64;
    #pragma unroll
    for (int i = 0; i < 4; i++) glds16(aS[i] + ko, &As[dst[i]]);
    #pragma unroll
    for (int i = 0; i < 4; i++) glds16(bS[i] + ko, &Bs[dst[i]]);
    __syncthreads();
    #pragma unroll
    for (int kc = 0; kc < 2; kc++){
      short8 afr[4], bfr[4];
      #pragma unroll
      for (int m = 0; m < 4; m++){
        int row  = wm * 64 + m * 16 + fr;
        int slot = (kc * 4 + fq) ^ (row & 7);
        afr[m] = *(const short8*)&As[row * 64 + slot * 8];
      }
      #pragma unroll
      for (int n = 0; n < 4; n++){
        int row  = wn * 64 + n * 16 + fr;
        int slot = (kc * 4 + fq) ^ (row & 7);
        bfr[n] = *(const short8*)&Bs[row * 64 + slot * 8];
      }
      #pragma unroll
      for (int m = 0; m < 4; m++)
        #pragma unroll
        for (int n = 0; n < 4; n++)
          acc[m][n] = __builtin_amdgcn_mfma_f32_16x16x32_bf16(afr[m], bfr[n], acc[m][n], 0, 0, 0);
    }
  }

  #pragma unroll
  for (int n = 0; n < 4; n++){
    int col = n0 + wn * 64 + n * 16 + fr;
    float bv = (sk == 0) ? bias[(size_t)e * DM + col] : 0.f;
    #pragma unroll
    for (int m = 0; m < 4; m++){
      int rbase = m0 + wm * 64 + m * 16 + fq * 4;
      f32x4 v = acc[m][n];
      #pragma unroll
      for (int i = 0; i < 4; i++){
        int mrow = rbase + i;
        if (mrow < ne){
          int tok = lst[mrow];
          pOut[((size_t)sk * T_TOK + tok) * DM + col] = v[i] + bv;
        }
      }
    }
  }
}

// out = gate * (part0+part1+part2+part3)   (b2 already in part0)
__global__ __launch_bounds__(256) void reduce_kernel(
    const float* __restrict__ part, const float* __restrict__ gate,
    float* __restrict__ out)
{
  size_t i = (size_t)blockIdx.x * 256 + threadIdx.x;
  constexpr size_t S = (size_t)T_TOK * DM / 4;
  const float4* p = (const float4*)part;
  float4 a = p[i], b = p[i + S], c = p[i + 2 * S], d = p[i + 3 * S];
  float g = gate[i >> 8];
  float4 o;
  o.x = (a.x + b.x + c.x + d.x) * g;
  o.y = (a.y + b.y + c.y + d.y) * g;
  o.z = (a.z + b.z + c.z + d.z) * g;
  o.w = (a.w + b.w + c.w + d.w) * g;
  ((float4*)out)[i] = o;
}

extern "C" void kernel_launch(void* const* d_in, const int* in_sizes, int n_in,
                              void* d_out, int out_size, void* d_ws, size_t ws_size,
                              hipStream_t stream) {
  const float* x   = (const float*)d_in[0];
  const float* gw  = (const float*)d_in[1];
  const float* w1  = (const float*)d_in[2];
  const float* b1  = (const float*)d_in[3];
  const float* w2  = (const float*)d_in[4];
  const float* b2  = (const float*)d_in[5];

  char* ws = (char*)d_ws;
  float* gateo = (float*)(ws + GATE_OFF);
  int*   cnt   = (int*)  (ws + CNT_OFF);
  int*   list  = (int*)  (ws + LIST_OFF);
  float* probs = (float*)(ws + PROBS_OFF);
  u16*   xb    = (u16*)  (ws + XB_OFF);
  u16*   h     = (u16*)  (ws + H_OFF);
  u16*   w1b   = (u16*)  (ws + W1B_OFF);
  float* part  = (float*)(ws + PART_OFF);   // overlays w1b (dead after GEMM1)
  u16*   w2b   = (u16*)  (ws + W2B_OFF);

  float* out = (float*)d_out;
  float* aux = out + (size_t)T_TOK * DM;

  hipLaunchKernelGGL(zero_cnt_kernel, dim3(1), dim3(64), 0, stream, cnt);
  // gate (1024 blocks) fused with cvt-w1 tail (2048 blocks)
  hipLaunchKernelGGL(gate_kernel, dim3(1024 + 2048), dim3(256), 0, stream,
                     x, gw, gateo, cnt, list, probs, xb, w1, w1b);
  hipLaunchKernelGGL(aux_kernel, dim3(1), dim3(256), 0, stream, probs, cnt, aux);

  // GEMM1 (bf16 w1b, L3-hot) fused with cvt-w2 tail blocks
  hipLaunchKernelGGL(ffn_gemm1, dim3(NG1 + 512), dim3(256), 0, stream,
                     xb, w1b, b1, cnt, list, h, w2, w2b);
  // GEMM2 (bf16 w2b), split-K=4 -> PART
  hipLaunchKernelGGL(ffn_gemm2, dim3(4 * MAXT * 8), dim3(256), 0, stream,
                     h, w2b, b2, cnt, list, part);
  hipLaunchKernelGGL(reduce_kernel, dim3(T_TOK * DM / 4 / 256), dim3(256), 0, stream,
                     part, gateo, out);
}